// Round 5
// baseline (1566.046 us; speedup 1.0000x reference)
//
#include <hip/hip_runtime.h>

// ---------------- CSR build ----------------

__global__ void degree_kernel(const int* __restrict__ ei, int* __restrict__ deg, int E) {
    int e = blockIdx.x * blockDim.x + threadIdx.x;
    if (e < E) {
        int dst = ei[E + e];
        atomicAdd(&deg[dst], 1);
    }
}

__global__ void scan_inv_kernel(const int* __restrict__ deg, int* __restrict__ offs,
                                float* __restrict__ invd, int n) {
    __shared__ int sums[1024];
    int tid = threadIdx.x;
    int chunk = (n + 1023) >> 10;
    int start = tid * chunk;
    int end = min(start + chunk, n);
    int s = 0;
    for (int i = start; i < end; i++) s += deg[i];
    sums[tid] = s;
    __syncthreads();
    for (int off = 1; off < 1024; off <<= 1) {
        int v = 0;
        if (tid >= off) v = sums[tid - off];
        __syncthreads();
        if (tid >= off) sums[tid] += v;
        __syncthreads();
    }
    int base = (tid == 0) ? 0 : sums[tid - 1];
    for (int i = start; i < end; i++) {
        offs[i] = base;
        int d = deg[i];
        base += d;
        invd[i] = 1.0f / (float)(d > 0 ? d : 1);
    }
    if (tid == 0) offs[n] = sums[1023];
}

__global__ void fill_kernel(const int* __restrict__ ei, const int* __restrict__ offs,
                            int* __restrict__ cursor, int* __restrict__ csr, int E) {
    int e = blockIdx.x * blockDim.x + threadIdx.x;
    if (e < E) {
        int src = ei[e];
        int dst = ei[E + e];
        int pos = atomicAdd(&cursor[dst], 1);
        csr[offs[dst] + pos] = src;
    }
}

// ---------------- mean aggregation: one wave per node ----------------

template <int D>
__global__ __launch_bounds__(256) void aggregate_kernel(
    const float* __restrict__ h, const int* __restrict__ offs,
    const int* __restrict__ csr, const float* __restrict__ invd,
    float* __restrict__ mean, int nN)
{
    int wid = blockIdx.x * 4 + (threadIdx.x >> 6);
    int lane = threadIdx.x & 63;
    if (wid >= nN) return;
    int o0 = offs[wid], o1 = offs[wid + 1];
    constexpr int C = D / 64;
    float acc[C];
#pragma unroll
    for (int c = 0; c < C; c++) acc[c] = 0.f;
    int j = o0;
    for (; j + 1 < o1; j += 2) {
        int s0 = csr[j], s1 = csr[j + 1];
        const float* r0 = h + (size_t)s0 * D;
        const float* r1 = h + (size_t)s1 * D;
#pragma unroll
        for (int c = 0; c < C; c++) acc[c] += r0[lane + 64 * c];
#pragma unroll
        for (int c = 0; c < C; c++) acc[c] += r1[lane + 64 * c];
    }
    if (j < o1) {
        const float* r0 = h + (size_t)csr[j] * D;
#pragma unroll
        for (int c = 0; c < C; c++) acc[c] += r0[lane + 64 * c];
    }
    float iv = invd[wid];
#pragma unroll
    for (int c = 0; c < C; c++) mean[(size_t)wid * D + lane + 64 * c] = acc[c] * iv;
}

// ---------------- fused dual GEMM + bias + ReLU ----------------
// out[n,m] = relu( sum_k A1[n,k]*wl[k,m] + bias[m] + sum_k A2[n,k]*wr[k,m] )
// 64-row tile per block. BOTH operands staged in LDS so the inner loop has no
// global loads (round-1 version spilled: 256 VGPR, 462 MB scratch writes).

template <int K, int M>
__global__ __launch_bounds__(256, 4) void gemm_relu_kernel(
    const float* __restrict__ A1, const float* __restrict__ A2,
    const float* __restrict__ wl, const float* __restrict__ wr,
    const float* __restrict__ bias, float* __restrict__ out, int nN)
{
    constexpr int TX = M / 4;       // threads across columns (float4 each)
    constexpr int TY = 256 / TX;
    constexpr int TR = 64 / TY;     // rows per thread
    __shared__ float a_s[32][65];   // [k-chunk][row], padded
    __shared__ float w_s[32][M];    // [k-chunk][col]

    int tid = threadIdx.x;
    int tx = tid % TX, ty = tid / TX;
    int n0 = blockIdx.x * 64;

    float4 bv = *(const float4*)(bias + tx * 4);
    float4 acc[TR];
#pragma unroll
    for (int r = 0; r < TR; r++) acc[r] = bv;

    int lr = tid >> 3;            // 0..31
    int lc = (tid & 7) << 2;      // 0,4,...,28

#pragma unroll
    for (int pass = 0; pass < 2; pass++) {
        const float* __restrict__ A = pass ? A2 : A1;
        const float* __restrict__ W = pass ? wr : wl;
        for (int k0 = 0; k0 < K; k0 += 32) {
            __syncthreads();   // protect previous chunk's reads
            // stage A chunk (64 rows x 32 k), transposed
#pragma unroll
            for (int rr = 0; rr < 64; rr += 32) {
                int gr = n0 + lr + rr;
                float4 v = make_float4(0.f, 0.f, 0.f, 0.f);
                if (gr < nN) v = *(const float4*)(A + (size_t)gr * K + k0 + lc);
                a_s[lc + 0][lr + rr] = v.x;
                a_s[lc + 1][lr + rr] = v.y;
                a_s[lc + 2][lr + rr] = v.z;
                a_s[lc + 3][lr + rr] = v.w;
            }
            // stage W chunk (32 k x M cols)
#pragma unroll
            for (int i = tid; i < 32 * (M / 4); i += 256) {
                int r = i / (M / 4);
                int c = i % (M / 4);
                float4 v = *(const float4*)(W + (size_t)(k0 + r) * M + c * 4);
                *(float4*)(&w_s[r][c * 4]) = v;
            }
            __syncthreads();
#pragma unroll
            for (int kk = 0; kk < 32; kk++) {
                float4 w4 = *(const float4*)(&w_s[kk][tx * 4]);
#pragma unroll
                for (int r = 0; r < TR; r++) {
                    float a = a_s[kk][ty * TR + r];
                    acc[r].x = fmaf(a, w4.x, acc[r].x);
                    acc[r].y = fmaf(a, w4.y, acc[r].y);
                    acc[r].z = fmaf(a, w4.z, acc[r].z);
                    acc[r].w = fmaf(a, w4.w, acc[r].w);
                }
            }
        }
    }

#pragma unroll
    for (int r = 0; r < TR; r++) {
        int n = n0 + ty * TR + r;
        if (n < nN) {
            float4 v = acc[r];
            v.x = fmaxf(v.x, 0.f); v.y = fmaxf(v.y, 0.f);
            v.z = fmaxf(v.z, 0.f); v.w = fmaxf(v.w, 0.f);
            *(float4*)(out + (size_t)n * M + tx * 4) = v;
        }
    }
}

// ---------------- classifier: [N,32] @ [32,2] + bc ----------------

__global__ void classifier_kernel(const float* __restrict__ h,
                                  const float* __restrict__ wc,
                                  const float* __restrict__ bc,
                                  float* __restrict__ out, int nN) {
    int n = blockIdx.x * blockDim.x + threadIdx.x;
    if (n >= nN) return;
    float a0 = bc[0], a1 = bc[1];
    const float* row = h + (size_t)n * 32;
#pragma unroll
    for (int k = 0; k < 32; k++) {
        float v = row[k];
        a0 = fmaf(v, wc[k * 2 + 0], a0);
        a1 = fmaf(v, wc[k * 2 + 1], a1);
    }
    out[n * 2 + 0] = a0;
    out[n * 2 + 1] = a1;
}

// ---------------- launch ----------------

extern "C" void kernel_launch(void* const* d_in, const int* in_sizes, int n_in,
                              void* d_out, int out_size, void* d_ws, size_t ws_size,
                              hipStream_t stream) {
    const float* x   = (const float*)d_in[0];
    const int*   ei  = (const int*)d_in[1];   // [2,E] int32
    const float* w1l = (const float*)d_in[2];
    const float* b1l = (const float*)d_in[3];
    const float* w1r = (const float*)d_in[4];
    const float* w2l = (const float*)d_in[5];
    const float* b2l = (const float*)d_in[6];
    const float* w2r = (const float*)d_in[7];
    const float* w3l = (const float*)d_in[8];
    const float* b3l = (const float*)d_in[9];
    const float* w3r = (const float*)d_in[10];
    const float* wc  = (const float*)d_in[11];
    const float* bc  = (const float*)d_in[12];
    float* out = (float*)d_out;

    const int N = in_sizes[0] / 128;
    const int E = in_sizes[1] / 2;

    char* p = (char*)d_ws;
    auto alloc = [&](size_t bytes) {
        char* r = p;
        p += (bytes + 511) & ~(size_t)511;
        return r;
    };
    int*   deg    = (int*)  alloc((size_t)N * 4);
    int*   offs   = (int*)  alloc(((size_t)N + 1) * 4);
    int*   cursor = (int*)  alloc((size_t)N * 4);
    float* invd   = (float*)alloc((size_t)N * 4);
    int*   csr    = (int*)  alloc((size_t)E * 4);
    float* mean   = (float*)alloc((size_t)N * 128 * 4);
    float* h1     = (float*)alloc((size_t)N * 128 * 4);
    float* h2     = (float*)alloc((size_t)N * 64 * 4);
    float* h3     = (float*)alloc((size_t)N * 32 * 4);

    hipMemsetAsync(deg, 0, (size_t)N * 4, stream);
    hipMemsetAsync(cursor, 0, (size_t)N * 4, stream);

    int eb = (E + 255) / 256;
    degree_kernel<<<eb, 256, 0, stream>>>(ei, deg, E);
    scan_inv_kernel<<<1, 1024, 0, stream>>>(deg, offs, invd, N);
    fill_kernel<<<eb, 256, 0, stream>>>(ei, offs, cursor, csr, E);

    int ab = (N + 3) / 4;
    int gb = (N + 63) / 64;

    aggregate_kernel<128><<<ab, 256, 0, stream>>>(x, offs, csr, invd, mean, N);
    gemm_relu_kernel<128, 128><<<gb, 256, 0, stream>>>(mean, x, w1l, w1r, b1l, h1, N);

    aggregate_kernel<128><<<ab, 256, 0, stream>>>(h1, offs, csr, invd, mean, N);
    gemm_relu_kernel<128, 64><<<gb, 256, 0, stream>>>(mean, h1, w2l, w2r, b2l, h2, N);

    aggregate_kernel<64><<<ab, 256, 0, stream>>>(h2, offs, csr, invd, mean, N);
    gemm_relu_kernel<64, 32><<<gb, 256, 0, stream>>>(mean, h2, w3l, w3r, b3l, h3, N);

    classifier_kernel<<<(N + 255) / 256, 256, 0, stream>>>(h3, wc, bc, out, N);
}

// Round 6
// 1088.526 us; speedup vs baseline: 1.4387x; 1.4387x over previous
//
#include <hip/hip_runtime.h>

// ---------------- CSR build ----------------

__global__ void degree_kernel(const int* __restrict__ ei, int* __restrict__ deg, int E) {
    int e = blockIdx.x * blockDim.x + threadIdx.x;
    if (e < E) {
        int dst = ei[E + e];
        atomicAdd(&deg[dst], 1);
    }
}

__global__ void scan_inv_kernel(const int* __restrict__ deg, int* __restrict__ offs,
                                float* __restrict__ invd, int n) {
    __shared__ int sums[1024];
    int tid = threadIdx.x;
    int chunk = (n + 1023) >> 10;
    int start = tid * chunk;
    int end = min(start + chunk, n);
    int s = 0;
    for (int i = start; i < end; i++) s += deg[i];
    sums[tid] = s;
    __syncthreads();
    for (int off = 1; off < 1024; off <<= 1) {
        int v = 0;
        if (tid >= off) v = sums[tid - off];
        __syncthreads();
        if (tid >= off) sums[tid] += v;
        __syncthreads();
    }
    int base = (tid == 0) ? 0 : sums[tid - 1];
    for (int i = start; i < end; i++) {
        offs[i] = base;
        int d = deg[i];
        base += d;
        invd[i] = 1.0f / (float)(d > 0 ? d : 1);
    }
    if (tid == 0) offs[n] = sums[1023];
}

__global__ void fill_kernel(const int* __restrict__ ei, const int* __restrict__ offs,
                            int* __restrict__ cursor, int* __restrict__ csr, int E) {
    int e = blockIdx.x * blockDim.x + threadIdx.x;
    if (e < E) {
        int src = ei[e];
        int dst = ei[E + e];
        int pos = atomicAdd(&cursor[dst], 1);
        csr[offs[dst] + pos] = src;
    }
}

// ---------------- mean aggregation: one wave per node ----------------

template <int D>
__global__ __launch_bounds__(256) void aggregate_kernel(
    const float* __restrict__ h, const int* __restrict__ offs,
    const int* __restrict__ csr, const float* __restrict__ invd,
    float* __restrict__ mean, int nN)
{
    int wid = blockIdx.x * 4 + (threadIdx.x >> 6);
    int lane = threadIdx.x & 63;
    if (wid >= nN) return;
    int o0 = offs[wid], o1 = offs[wid + 1];
    constexpr int C = D / 64;
    float acc[C];
#pragma unroll
    for (int c = 0; c < C; c++) acc[c] = 0.f;
    int j = o0;
    for (; j + 1 < o1; j += 2) {
        int s0 = csr[j], s1 = csr[j + 1];
        const float* r0 = h + (size_t)s0 * D;
        const float* r1 = h + (size_t)s1 * D;
#pragma unroll
        for (int c = 0; c < C; c++) acc[c] += r0[lane + 64 * c];
#pragma unroll
        for (int c = 0; c < C; c++) acc[c] += r1[lane + 64 * c];
    }
    if (j < o1) {
        const float* r0 = h + (size_t)csr[j] * D;
#pragma unroll
        for (int c = 0; c < C; c++) acc[c] += r0[lane + 64 * c];
    }
    float iv = invd[wid];
#pragma unroll
    for (int c = 0; c < C; c++) mean[(size_t)wid * D + lane + 64 * c] = acc[c] * iv;
}

// ---------------- fused dual GEMM + bias + ReLU (streaming, no LDS) ----------------
// out[n,m..m+3] per thread over R consecutive rows. Lanes sharing a row-group
// load the same A float4 (HW broadcast); W is L1/L2-resident (<=64 KB/matrix).
// No LDS, no barriers: the round-1/5 LDS-tiled versions both showed >10x
// HBM-traffic amplification; this structure can't generate hidden traffic.

__device__ inline void fma4(float4& a, float s, const float4& w) {
    a.x = fmaf(s, w.x, a.x);
    a.y = fmaf(s, w.y, a.y);
    a.z = fmaf(s, w.z, a.z);
    a.w = fmaf(s, w.w, a.w);
}

template <int K, int M, int R>
__global__ __launch_bounds__(256, 4) void gemm_relu_stream(
    const float* __restrict__ A1, const float* __restrict__ A2,
    const float* __restrict__ wl, const float* __restrict__ wr,
    const float* __restrict__ bias, float* __restrict__ out, int nN)
{
    constexpr int TXc = M / 4;            // threads per row-group
    constexpr int GROUPS = 256 / TXc;     // row-groups per block
    const int tid = threadIdx.x;
    const int cq = (tid % TXc) * 4;       // column base for this thread
    const int g = tid / TXc;
    const int n0 = (blockIdx.x * GROUPS + g) * R;

    const float4 bv = *(const float4*)(bias + cq);
    float4 acc[R];
#pragma unroll
    for (int rr = 0; rr < R; rr++) acc[rr] = bv;

    for (int k = 0; k < K; k += 4) {
        float4 wl0 = *(const float4*)(wl + (size_t)(k + 0) * M + cq);
        float4 wl1 = *(const float4*)(wl + (size_t)(k + 1) * M + cq);
        float4 wl2 = *(const float4*)(wl + (size_t)(k + 2) * M + cq);
        float4 wl3 = *(const float4*)(wl + (size_t)(k + 3) * M + cq);
        float4 wr0 = *(const float4*)(wr + (size_t)(k + 0) * M + cq);
        float4 wr1 = *(const float4*)(wr + (size_t)(k + 1) * M + cq);
        float4 wr2 = *(const float4*)(wr + (size_t)(k + 2) * M + cq);
        float4 wr3 = *(const float4*)(wr + (size_t)(k + 3) * M + cq);
#pragma unroll
        for (int rr = 0; rr < R; rr++) {
            int n = n0 + rr;
            if (n < nN) {
                float4 a1 = *(const float4*)(A1 + (size_t)n * K + k);
                float4 a2 = *(const float4*)(A2 + (size_t)n * K + k);
                fma4(acc[rr], a1.x, wl0);
                fma4(acc[rr], a1.y, wl1);
                fma4(acc[rr], a1.z, wl2);
                fma4(acc[rr], a1.w, wl3);
                fma4(acc[rr], a2.x, wr0);
                fma4(acc[rr], a2.y, wr1);
                fma4(acc[rr], a2.z, wr2);
                fma4(acc[rr], a2.w, wr3);
            }
        }
    }

#pragma unroll
    for (int rr = 0; rr < R; rr++) {
        int n = n0 + rr;
        if (n < nN) {
            float4 v = acc[rr];
            v.x = fmaxf(v.x, 0.f); v.y = fmaxf(v.y, 0.f);
            v.z = fmaxf(v.z, 0.f); v.w = fmaxf(v.w, 0.f);
            *(float4*)(out + (size_t)n * M + cq) = v;
        }
    }
}

// ---------------- classifier: [N,32] @ [32,2] + bc ----------------

__global__ void classifier_kernel(const float* __restrict__ h,
                                  const float* __restrict__ wc,
                                  const float* __restrict__ bc,
                                  float* __restrict__ out, int nN) {
    int n = blockIdx.x * blockDim.x + threadIdx.x;
    if (n >= nN) return;
    float a0 = bc[0], a1 = bc[1];
    const float* row = h + (size_t)n * 32;
#pragma unroll
    for (int k = 0; k < 32; k++) {
        float v = row[k];
        a0 = fmaf(v, wc[k * 2 + 0], a0);
        a1 = fmaf(v, wc[k * 2 + 1], a1);
    }
    out[n * 2 + 0] = a0;
    out[n * 2 + 1] = a1;
}

// ---------------- launch ----------------

extern "C" void kernel_launch(void* const* d_in, const int* in_sizes, int n_in,
                              void* d_out, int out_size, void* d_ws, size_t ws_size,
                              hipStream_t stream) {
    const float* x   = (const float*)d_in[0];
    const int*   ei  = (const int*)d_in[1];   // [2,E] int32
    const float* w1l = (const float*)d_in[2];
    const float* b1l = (const float*)d_in[3];
    const float* w1r = (const float*)d_in[4];
    const float* w2l = (const float*)d_in[5];
    const float* b2l = (const float*)d_in[6];
    const float* w2r = (const float*)d_in[7];
    const float* w3l = (const float*)d_in[8];
    const float* b3l = (const float*)d_in[9];
    const float* w3r = (const float*)d_in[10];
    const float* wc  = (const float*)d_in[11];
    const float* bc  = (const float*)d_in[12];
    float* out = (float*)d_out;

    const int N = in_sizes[0] / 128;
    const int E = in_sizes[1] / 2;

    char* p = (char*)d_ws;
    auto alloc = [&](size_t bytes) {
        char* r = p;
        p += (bytes + 511) & ~(size_t)511;
        return r;
    };
    int*   deg    = (int*)  alloc((size_t)N * 4);
    int*   offs   = (int*)  alloc(((size_t)N + 1) * 4);
    int*   cursor = (int*)  alloc((size_t)N * 4);
    float* invd   = (float*)alloc((size_t)N * 4);
    int*   csr    = (int*)  alloc((size_t)E * 4);
    float* mean   = (float*)alloc((size_t)N * 128 * 4);
    float* h1     = (float*)alloc((size_t)N * 128 * 4);
    float* h2     = (float*)alloc((size_t)N * 64 * 4);
    float* h3     = (float*)alloc((size_t)N * 32 * 4);

    hipMemsetAsync(deg, 0, (size_t)N * 4, stream);
    hipMemsetAsync(cursor, 0, (size_t)N * 4, stream);

    int eb = (E + 255) / 256;
    degree_kernel<<<eb, 256, 0, stream>>>(ei, deg, E);
    scan_inv_kernel<<<1, 1024, 0, stream>>>(deg, offs, invd, N);
    fill_kernel<<<eb, 256, 0, stream>>>(ei, offs, cursor, csr, E);

    int ab = (N + 3) / 4;

    // rows per block = (256/(M/4)) * R
    constexpr int R = 4;
    int g1 = (N + (256 / (128 / 4)) * R - 1) / ((256 / (128 / 4)) * R);   // 32 rows/blk
    int g2 = (N + (256 / (64 / 4)) * R - 1) / ((256 / (64 / 4)) * R);     // 64 rows/blk
    int g3 = (N + (256 / (32 / 4)) * R - 1) / ((256 / (32 / 4)) * R);     // 128 rows/blk

    aggregate_kernel<128><<<ab, 256, 0, stream>>>(x, offs, csr, invd, mean, N);
    gemm_relu_stream<128, 128, R><<<g1, 256, 0, stream>>>(mean, x, w1l, w1r, b1l, h1, N);

    aggregate_kernel<128><<<ab, 256, 0, stream>>>(h1, offs, csr, invd, mean, N);
    gemm_relu_stream<128, 64, R><<<g2, 256, 0, stream>>>(mean, h1, w2l, w2r, b2l, h2, N);

    aggregate_kernel<64><<<ab, 256, 0, stream>>>(h2, offs, csr, invd, mean, N);
    gemm_relu_stream<64, 32, R><<<g3, 256, 0, stream>>>(mean, h2, w3l, w3r, b3l, h3, N);

    classifier_kernel<<<(N + 255) / 256, 256, 0, stream>>>(h3, wc, bc, out, N);
}

// Round 7
// 871.944 us; speedup vs baseline: 1.7960x; 1.2484x over previous
//
#include <hip/hip_runtime.h>

// ---------------- CSR build ----------------

__global__ void degree_kernel(const int* __restrict__ ei, int* __restrict__ deg, int E) {
    int e = blockIdx.x * blockDim.x + threadIdx.x;
    if (e < E) {
        int dst = ei[E + e];
        atomicAdd(&deg[dst], 1);
    }
}

// ---- hierarchical exclusive scan of deg -> offs (+ invd) ----
// (round-6 profile: single-block scan was 224 us on 1 CU; 20% of runtime)

__global__ __launch_bounds__(512) void block_sum_kernel(
    const int* __restrict__ deg, int* __restrict__ bsum, int n)
{
    __shared__ int s[512];
    int i = blockIdx.x * 512 + threadIdx.x;
    s[threadIdx.x] = (i < n) ? deg[i] : 0;
    __syncthreads();
#pragma unroll
    for (int off = 256; off > 0; off >>= 1) {
        if (threadIdx.x < off) s[threadIdx.x] += s[threadIdx.x + off];
        __syncthreads();
    }
    if (threadIdx.x == 0) bsum[blockIdx.x] = s[0];
}

__global__ __launch_bounds__(1024) void bsum_scan_kernel(int* __restrict__ bsum, int nb) {
    // single block: exclusive scan in place (nb <= 1024)
    __shared__ int s[1024];
    int t = threadIdx.x;
    s[t] = (t < nb) ? bsum[t] : 0;
    __syncthreads();
    for (int off = 1; off < 1024; off <<= 1) {
        int v = 0;
        if (t >= off) v = s[t - off];
        __syncthreads();
        if (t >= off) s[t] += v;
        __syncthreads();
    }
    if (t < nb) bsum[t] = (t == 0) ? 0 : s[t - 1];
}

__global__ __launch_bounds__(512) void scan_write_kernel(
    const int* __restrict__ deg, const int* __restrict__ bsum,
    int* __restrict__ offs, float* __restrict__ invd, int n, int E)
{
    __shared__ int s[512];
    int t = threadIdx.x;
    int i = blockIdx.x * 512 + t;
    int d = (i < n) ? deg[i] : 0;
    s[t] = d;
    __syncthreads();
    for (int off = 1; off < 512; off <<= 1) {
        int v = 0;
        if (t >= off) v = s[t - off];
        __syncthreads();
        if (t >= off) s[t] += v;
        __syncthreads();
    }
    if (i < n) {
        offs[i] = bsum[blockIdx.x] + s[t] - d;   // exclusive prefix
        invd[i] = 1.0f / (float)(d > 0 ? d : 1);
    }
    if (blockIdx.x == 0 && t == 0) offs[n] = E;
}

__global__ void fill_kernel(const int* __restrict__ ei, const int* __restrict__ offs,
                            int* __restrict__ cursor, int* __restrict__ csr, int E) {
    int e = blockIdx.x * blockDim.x + threadIdx.x;
    if (e < E) {
        int src = ei[e];
        int dst = ei[E + e];
        int pos = atomicAdd(&cursor[dst], 1);
        csr[offs[dst] + pos] = src;
    }
}

// ---------------- mean aggregation: one wave per node ----------------

template <int D>
__global__ __launch_bounds__(256) void aggregate_kernel(
    const float* __restrict__ h, const int* __restrict__ offs,
    const int* __restrict__ csr, const float* __restrict__ invd,
    float* __restrict__ mean, int nN)
{
    int wid = blockIdx.x * 4 + (threadIdx.x >> 6);
    int lane = threadIdx.x & 63;
    if (wid >= nN) return;
    int o0 = offs[wid], o1 = offs[wid + 1];
    constexpr int C = D / 64;
    float acc[C];
#pragma unroll
    for (int c = 0; c < C; c++) acc[c] = 0.f;
    int j = o0;
    for (; j + 1 < o1; j += 2) {
        int s0 = csr[j], s1 = csr[j + 1];
        const float* r0 = h + (size_t)s0 * D;
        const float* r1 = h + (size_t)s1 * D;
#pragma unroll
        for (int c = 0; c < C; c++) acc[c] += r0[lane + 64 * c];
#pragma unroll
        for (int c = 0; c < C; c++) acc[c] += r1[lane + 64 * c];
    }
    if (j < o1) {
        const float* r0 = h + (size_t)csr[j] * D;
#pragma unroll
        for (int c = 0; c < C; c++) acc[c] += r0[lane + 64 * c];
    }
    float iv = invd[wid];
#pragma unroll
    for (int c = 0; c < C; c++) mean[(size_t)wid * D + lane + 64 * c] = acc[c] * iv;
}

// ---------------- fused dual GEMM + bias + ReLU (streaming, no LDS) ----------------

__device__ inline void fma4(float4& a, float s, const float4& w) {
    a.x = fmaf(s, w.x, a.x);
    a.y = fmaf(s, w.y, a.y);
    a.z = fmaf(s, w.z, a.z);
    a.w = fmaf(s, w.w, a.w);
}

template <int K, int M, int R>
__global__ __launch_bounds__(256, 4) void gemm_relu_stream(
    const float* __restrict__ A1, const float* __restrict__ A2,
    const float* __restrict__ wl, const float* __restrict__ wr,
    const float* __restrict__ bias, float* __restrict__ out, int nN)
{
    constexpr int TXc = M / 4;            // threads per row-group
    constexpr int GROUPS = 256 / TXc;     // row-groups per block
    const int tid = threadIdx.x;
    const int cq = (tid % TXc) * 4;       // column base for this thread
    const int g = tid / TXc;
    const int n0 = (blockIdx.x * GROUPS + g) * R;

    const float4 bv = *(const float4*)(bias + cq);
    float4 acc[R];
#pragma unroll
    for (int rr = 0; rr < R; rr++) acc[rr] = bv;

    for (int k = 0; k < K; k += 4) {
        float4 wl0 = *(const float4*)(wl + (size_t)(k + 0) * M + cq);
        float4 wl1 = *(const float4*)(wl + (size_t)(k + 1) * M + cq);
        float4 wl2 = *(const float4*)(wl + (size_t)(k + 2) * M + cq);
        float4 wl3 = *(const float4*)(wl + (size_t)(k + 3) * M + cq);
        float4 wr0 = *(const float4*)(wr + (size_t)(k + 0) * M + cq);
        float4 wr1 = *(const float4*)(wr + (size_t)(k + 1) * M + cq);
        float4 wr2 = *(const float4*)(wr + (size_t)(k + 2) * M + cq);
        float4 wr3 = *(const float4*)(wr + (size_t)(k + 3) * M + cq);
#pragma unroll
        for (int rr = 0; rr < R; rr++) {
            int n = n0 + rr;
            if (n < nN) {
                float4 a1 = *(const float4*)(A1 + (size_t)n * K + k);
                float4 a2 = *(const float4*)(A2 + (size_t)n * K + k);
                fma4(acc[rr], a1.x, wl0);
                fma4(acc[rr], a1.y, wl1);
                fma4(acc[rr], a1.z, wl2);
                fma4(acc[rr], a1.w, wl3);
                fma4(acc[rr], a2.x, wr0);
                fma4(acc[rr], a2.y, wr1);
                fma4(acc[rr], a2.z, wr2);
                fma4(acc[rr], a2.w, wr3);
            }
        }
    }

#pragma unroll
    for (int rr = 0; rr < R; rr++) {
        int n = n0 + rr;
        if (n < nN) {
            float4 v = acc[rr];
            v.x = fmaxf(v.x, 0.f); v.y = fmaxf(v.y, 0.f);
            v.z = fmaxf(v.z, 0.f); v.w = fmaxf(v.w, 0.f);
            *(float4*)(out + (size_t)n * M + cq) = v;
        }
    }
}

// ---------------- classifier: [N,32] @ [32,2] + bc ----------------

__global__ void classifier_kernel(const float* __restrict__ h,
                                  const float* __restrict__ wc,
                                  const float* __restrict__ bc,
                                  float* __restrict__ out, int nN) {
    int n = blockIdx.x * blockDim.x + threadIdx.x;
    if (n >= nN) return;
    float a0 = bc[0], a1 = bc[1];
    const float* row = h + (size_t)n * 32;
#pragma unroll
    for (int k = 0; k < 32; k++) {
        float v = row[k];
        a0 = fmaf(v, wc[k * 2 + 0], a0);
        a1 = fmaf(v, wc[k * 2 + 1], a1);
    }
    out[n * 2 + 0] = a0;
    out[n * 2 + 1] = a1;
}

// ---------------- launch ----------------

extern "C" void kernel_launch(void* const* d_in, const int* in_sizes, int n_in,
                              void* d_out, int out_size, void* d_ws, size_t ws_size,
                              hipStream_t stream) {
    const float* x   = (const float*)d_in[0];
    const int*   ei  = (const int*)d_in[1];   // [2,E] int32
    const float* w1l = (const float*)d_in[2];
    const float* b1l = (const float*)d_in[3];
    const float* w1r = (const float*)d_in[4];
    const float* w2l = (const float*)d_in[5];
    const float* b2l = (const float*)d_in[6];
    const float* w2r = (const float*)d_in[7];
    const float* w3l = (const float*)d_in[8];
    const float* b3l = (const float*)d_in[9];
    const float* w3r = (const float*)d_in[10];
    const float* wc  = (const float*)d_in[11];
    const float* bc  = (const float*)d_in[12];
    float* out = (float*)d_out;

    const int N = in_sizes[0] / 128;
    const int E = in_sizes[1] / 2;
    const int NB = (N + 511) / 512;           // scan blocks (<=1024)

    char* p = (char*)d_ws;
    auto alloc = [&](size_t bytes) {
        char* r = p;
        p += (bytes + 511) & ~(size_t)511;
        return r;
    };
    int*   deg    = (int*)  alloc((size_t)N * 4);
    int*   offs   = (int*)  alloc(((size_t)N + 1) * 4);
    int*   cursor = (int*)  alloc((size_t)N * 4);
    float* invd   = (float*)alloc((size_t)N * 4);
    int*   bsum   = (int*)  alloc((size_t)NB * 4);
    int*   csr    = (int*)  alloc((size_t)E * 4);
    float* mean   = (float*)alloc((size_t)N * 128 * 4);
    float* h1     = (float*)alloc((size_t)N * 128 * 4);
    float* h2     = (float*)alloc((size_t)N * 64 * 4);
    float* h3     = (float*)alloc((size_t)N * 32 * 4);

    hipMemsetAsync(deg, 0, (size_t)N * 4, stream);
    hipMemsetAsync(cursor, 0, (size_t)N * 4, stream);

    int eb = (E + 255) / 256;
    degree_kernel<<<eb, 256, 0, stream>>>(ei, deg, E);
    block_sum_kernel<<<NB, 512, 0, stream>>>(deg, bsum, N);
    bsum_scan_kernel<<<1, 1024, 0, stream>>>(bsum, NB);
    scan_write_kernel<<<NB, 512, 0, stream>>>(deg, bsum, offs, invd, N, E);
    fill_kernel<<<eb, 256, 0, stream>>>(ei, offs, cursor, csr, E);

    int ab = (N + 3) / 4;

    // rows per block = (256/(M/4)) * R
    constexpr int R = 4;
    int g1 = (N + (256 / (128 / 4)) * R - 1) / ((256 / (128 / 4)) * R);   // 32 rows/blk
    int g2 = (N + (256 / (64 / 4)) * R - 1) / ((256 / (64 / 4)) * R);     // 64 rows/blk
    int g3 = (N + (256 / (32 / 4)) * R - 1) / ((256 / (32 / 4)) * R);     // 128 rows/blk

    aggregate_kernel<128><<<ab, 256, 0, stream>>>(x, offs, csr, invd, mean, N);
    gemm_relu_stream<128, 128, R><<<g1, 256, 0, stream>>>(mean, x, w1l, w1r, b1l, h1, N);

    aggregate_kernel<128><<<ab, 256, 0, stream>>>(h1, offs, csr, invd, mean, N);
    gemm_relu_stream<128, 64, R><<<g2, 256, 0, stream>>>(mean, h1, w2l, w2r, b2l, h2, N);

    aggregate_kernel<64><<<ab, 256, 0, stream>>>(h2, offs, csr, invd, mean, N);
    gemm_relu_stream<64, 32, R><<<g3, 256, 0, stream>>>(mean, h2, w3l, w3r, b3l, h3, N);

    classifier_kernel<<<(N + 255) / 256, 256, 0, stream>>>(h3, wc, bc, out, N);
}

// Round 8
// 838.926 us; speedup vs baseline: 1.8667x; 1.0394x over previous
//
#include <hip/hip_runtime.h>

// ---------------- CSR build ----------------

__global__ void degree_kernel(const int* __restrict__ ei, int* __restrict__ deg, int E) {
    int e = blockIdx.x * blockDim.x + threadIdx.x;
    if (e < E) {
        int dst = ei[E + e];
        atomicAdd(&deg[dst], 1);
    }
}

// ---- hierarchical exclusive scan of deg -> offs (+ invd) ----

__global__ __launch_bounds__(512) void block_sum_kernel(
    const int* __restrict__ deg, int* __restrict__ bsum, int n)
{
    __shared__ int s[512];
    int i = blockIdx.x * 512 + threadIdx.x;
    s[threadIdx.x] = (i < n) ? deg[i] : 0;
    __syncthreads();
#pragma unroll
    for (int off = 256; off > 0; off >>= 1) {
        if (threadIdx.x < off) s[threadIdx.x] += s[threadIdx.x + off];
        __syncthreads();
    }
    if (threadIdx.x == 0) bsum[blockIdx.x] = s[0];
}

__global__ __launch_bounds__(1024) void bsum_scan_kernel(int* __restrict__ bsum, int nb) {
    __shared__ int s[1024];
    int t = threadIdx.x;
    s[t] = (t < nb) ? bsum[t] : 0;
    __syncthreads();
    for (int off = 1; off < 1024; off <<= 1) {
        int v = 0;
        if (t >= off) v = s[t - off];
        __syncthreads();
        if (t >= off) s[t] += v;
        __syncthreads();
    }
    if (t < nb) bsum[t] = (t == 0) ? 0 : s[t - 1];
}

__global__ __launch_bounds__(512) void scan_write_kernel(
    const int* __restrict__ deg, const int* __restrict__ bsum,
    int* __restrict__ offs, float* __restrict__ invd, int n, int E)
{
    __shared__ int s[512];
    int t = threadIdx.x;
    int i = blockIdx.x * 512 + t;
    int d = (i < n) ? deg[i] : 0;
    s[t] = d;
    __syncthreads();
    for (int off = 1; off < 512; off <<= 1) {
        int v = 0;
        if (t >= off) v = s[t - off];
        __syncthreads();
        if (t >= off) s[t] += v;
        __syncthreads();
    }
    if (i < n) {
        offs[i] = bsum[blockIdx.x] + s[t] - d;   // exclusive prefix
        invd[i] = 1.0f / (float)(d > 0 ? d : 1);
    }
    if (blockIdx.x == 0 && t == 0) offs[n] = E;
}

__global__ void fill_kernel(const int* __restrict__ ei, const int* __restrict__ offs,
                            int* __restrict__ cursor, int* __restrict__ csr, int E) {
    int e = blockIdx.x * blockDim.x + threadIdx.x;
    if (e < E) {
        int src = ei[e];
        int dst = ei[E + e];
        int pos = atomicAdd(&cursor[dst], 1);
        csr[offs[dst] + pos] = src;
    }
}

// ---------------- mean aggregation: one wave per node ----------------

template <int D>
__global__ __launch_bounds__(256) void aggregate_kernel(
    const float* __restrict__ h, const int* __restrict__ offs,
    const int* __restrict__ csr, const float* __restrict__ invd,
    float* __restrict__ mean, int nN)
{
    int wid = blockIdx.x * 4 + (threadIdx.x >> 6);
    int lane = threadIdx.x & 63;
    if (wid >= nN) return;
    int o0 = offs[wid], o1 = offs[wid + 1];
    constexpr int C = D / 64;
    float acc[C];
#pragma unroll
    for (int c = 0; c < C; c++) acc[c] = 0.f;
    int j = o0;
    for (; j + 1 < o1; j += 2) {
        int s0 = csr[j], s1 = csr[j + 1];
        const float* r0 = h + (size_t)s0 * D;
        const float* r1 = h + (size_t)s1 * D;
#pragma unroll
        for (int c = 0; c < C; c++) acc[c] += r0[lane + 64 * c];
#pragma unroll
        for (int c = 0; c < C; c++) acc[c] += r1[lane + 64 * c];
    }
    if (j < o1) {
        const float* r0 = h + (size_t)csr[j] * D;
#pragma unroll
        for (int c = 0; c < C; c++) acc[c] += r0[lane + 64 * c];
    }
    float iv = invd[wid];
#pragma unroll
    for (int c = 0; c < C; c++) mean[(size_t)wid * D + lane + 64 * c] = acc[c] * iv;
}

// ---------------- fused dual GEMM + bias + ReLU (streaming, no LDS) ----------------
// Round-7 profile: VALUBusy 24.7%, VGPR=40 — per-row `if` predicates between
// loads broke load batching; compiler serialized load->wait->FMA per pair.
// Fix: wave-uniform full-tile fast path, all 16 chunk loads issued unpredicated
// into register arrays -> one vmcnt wait per 128 FMAs.

__device__ inline void fma4(float4& a, float s, const float4& w) {
    a.x = fmaf(s, w.x, a.x);
    a.y = fmaf(s, w.y, a.y);
    a.z = fmaf(s, w.z, a.z);
    a.w = fmaf(s, w.w, a.w);
}

template <int K, int M, int R>
__global__ __launch_bounds__(256, 4) void gemm_relu_stream(
    const float* __restrict__ A1, const float* __restrict__ A2,
    const float* __restrict__ wl, const float* __restrict__ wr,
    const float* __restrict__ bias, float* __restrict__ out, int nN)
{
    constexpr int TXc = M / 4;            // threads per row-group
    constexpr int GROUPS = 256 / TXc;     // row-groups per block
    const int tid = threadIdx.x;
    const int cq = (tid % TXc) * 4;       // column base for this thread
    const int g = tid / TXc;
    const int n0 = (blockIdx.x * GROUPS + g) * R;
    if (n0 >= nN) return;                 // no barriers below: early-out safe

    const float4 bv = *(const float4*)(bias + cq);
    float4 acc[R];
#pragma unroll
    for (int rr = 0; rr < R; rr++) acc[rr] = bv;

    if (n0 + R <= nN) {
        // -------- fast path: full tile, unpredicated batched loads --------
        const float* __restrict__ a1p = A1 + (size_t)n0 * K;
        const float* __restrict__ a2p = A2 + (size_t)n0 * K;
        for (int k = 0; k < K; k += 4) {
            float4 wlv[4], wrv[4], a1v[R], a2v[R];
#pragma unroll
            for (int j = 0; j < 4; j++) {
                wlv[j] = *(const float4*)(wl + (size_t)(k + j) * M + cq);
                wrv[j] = *(const float4*)(wr + (size_t)(k + j) * M + cq);
            }
#pragma unroll
            for (int rr = 0; rr < R; rr++) {
                a1v[rr] = *(const float4*)(a1p + (size_t)rr * K + k);
                a2v[rr] = *(const float4*)(a2p + (size_t)rr * K + k);
            }
#pragma unroll
            for (int rr = 0; rr < R; rr++) {
                fma4(acc[rr], a1v[rr].x, wlv[0]);
                fma4(acc[rr], a1v[rr].y, wlv[1]);
                fma4(acc[rr], a1v[rr].z, wlv[2]);
                fma4(acc[rr], a1v[rr].w, wlv[3]);
                fma4(acc[rr], a2v[rr].x, wrv[0]);
                fma4(acc[rr], a2v[rr].y, wrv[1]);
                fma4(acc[rr], a2v[rr].z, wrv[2]);
                fma4(acc[rr], a2v[rr].w, wrv[3]);
            }
        }
#pragma unroll
        for (int rr = 0; rr < R; rr++) {
            float4 v = acc[rr];
            v.x = fmaxf(v.x, 0.f); v.y = fmaxf(v.y, 0.f);
            v.z = fmaxf(v.z, 0.f); v.w = fmaxf(v.w, 0.f);
            *(float4*)(out + (size_t)(n0 + rr) * M + cq) = v;
        }
    } else {
        // -------- slow path: partial tile (rare) --------
        for (int k = 0; k < K; k += 4) {
            float4 wlv[4], wrv[4];
#pragma unroll
            for (int j = 0; j < 4; j++) {
                wlv[j] = *(const float4*)(wl + (size_t)(k + j) * M + cq);
                wrv[j] = *(const float4*)(wr + (size_t)(k + j) * M + cq);
            }
#pragma unroll
            for (int rr = 0; rr < R; rr++) {
                int n = n0 + rr;
                if (n < nN) {
                    float4 a1 = *(const float4*)(A1 + (size_t)n * K + k);
                    float4 a2 = *(const float4*)(A2 + (size_t)n * K + k);
                    fma4(acc[rr], a1.x, wlv[0]);
                    fma4(acc[rr], a1.y, wlv[1]);
                    fma4(acc[rr], a1.z, wlv[2]);
                    fma4(acc[rr], a1.w, wlv[3]);
                    fma4(acc[rr], a2.x, wrv[0]);
                    fma4(acc[rr], a2.y, wrv[1]);
                    fma4(acc[rr], a2.z, wrv[2]);
                    fma4(acc[rr], a2.w, wrv[3]);
                }
            }
        }
#pragma unroll
        for (int rr = 0; rr < R; rr++) {
            int n = n0 + rr;
            if (n < nN) {
                float4 v = acc[rr];
                v.x = fmaxf(v.x, 0.f); v.y = fmaxf(v.y, 0.f);
                v.z = fmaxf(v.z, 0.f); v.w = fmaxf(v.w, 0.f);
                *(float4*)(out + (size_t)n * M + cq) = v;
            }
        }
    }
}

// ---------------- classifier: [N,32] @ [32,2] + bc ----------------

__global__ void classifier_kernel(const float* __restrict__ h,
                                  const float* __restrict__ wc,
                                  const float* __restrict__ bc,
                                  float* __restrict__ out, int nN) {
    int n = blockIdx.x * blockDim.x + threadIdx.x;
    if (n >= nN) return;
    float a0 = bc[0], a1 = bc[1];
    const float* row = h + (size_t)n * 32;
#pragma unroll
    for (int k = 0; k < 32; k++) {
        float v = row[k];
        a0 = fmaf(v, wc[k * 2 + 0], a0);
        a1 = fmaf(v, wc[k * 2 + 1], a1);
    }
    out[n * 2 + 0] = a0;
    out[n * 2 + 1] = a1;
}

// ---------------- launch ----------------

extern "C" void kernel_launch(void* const* d_in, const int* in_sizes, int n_in,
                              void* d_out, int out_size, void* d_ws, size_t ws_size,
                              hipStream_t stream) {
    const float* x   = (const float*)d_in[0];
    const int*   ei  = (const int*)d_in[1];   // [2,E] int32
    const float* w1l = (const float*)d_in[2];
    const float* b1l = (const float*)d_in[3];
    const float* w1r = (const float*)d_in[4];
    const float* w2l = (const float*)d_in[5];
    const float* b2l = (const float*)d_in[6];
    const float* w2r = (const float*)d_in[7];
    const float* w3l = (const float*)d_in[8];
    const float* b3l = (const float*)d_in[9];
    const float* w3r = (const float*)d_in[10];
    const float* wc  = (const float*)d_in[11];
    const float* bc  = (const float*)d_in[12];
    float* out = (float*)d_out;

    const int N = in_sizes[0] / 128;
    const int E = in_sizes[1] / 2;
    const int NB = (N + 511) / 512;           // scan blocks (<=1024)

    char* p = (char*)d_ws;
    auto alloc = [&](size_t bytes) {
        char* r = p;
        p += (bytes + 511) & ~(size_t)511;
        return r;
    };
    int*   deg    = (int*)  alloc((size_t)N * 4);
    int*   offs   = (int*)  alloc(((size_t)N + 1) * 4);
    int*   cursor = (int*)  alloc((size_t)N * 4);
    float* invd   = (float*)alloc((size_t)N * 4);
    int*   bsum   = (int*)  alloc((size_t)NB * 4);
    int*   csr    = (int*)  alloc((size_t)E * 4);
    float* mean   = (float*)alloc((size_t)N * 128 * 4);
    float* h1     = (float*)alloc((size_t)N * 128 * 4);
    float* h2     = (float*)alloc((size_t)N * 64 * 4);
    float* h3     = (float*)alloc((size_t)N * 32 * 4);

    hipMemsetAsync(deg, 0, (size_t)N * 4, stream);
    hipMemsetAsync(cursor, 0, (size_t)N * 4, stream);

    int eb = (E + 255) / 256;
    degree_kernel<<<eb, 256, 0, stream>>>(ei, deg, E);
    block_sum_kernel<<<NB, 512, 0, stream>>>(deg, bsum, N);
    bsum_scan_kernel<<<1, 1024, 0, stream>>>(bsum, NB);
    scan_write_kernel<<<NB, 512, 0, stream>>>(deg, bsum, offs, invd, N, E);
    fill_kernel<<<eb, 256, 0, stream>>>(ei, offs, cursor, csr, E);

    int ab = (N + 3) / 4;

    // rows per block = (256/(M/4)) * R
    constexpr int R = 4;
    int g1 = (N + (256 / (128 / 4)) * R - 1) / ((256 / (128 / 4)) * R);   // 32 rows/blk
    int g2 = (N + (256 / (64 / 4)) * R - 1) / ((256 / (64 / 4)) * R);     // 64 rows/blk
    int g3 = (N + (256 / (32 / 4)) * R - 1) / ((256 / (32 / 4)) * R);     // 128 rows/blk

    aggregate_kernel<128><<<ab, 256, 0, stream>>>(x, offs, csr, invd, mean, N);
    gemm_relu_stream<128, 128, R><<<g1, 256, 0, stream>>>(mean, x, w1l, w1r, b1l, h1, N);

    aggregate_kernel<128><<<ab, 256, 0, stream>>>(h1, offs, csr, invd, mean, N);
    gemm_relu_stream<128, 64, R><<<g2, 256, 0, stream>>>(mean, h1, w2l, w2r, b2l, h2, N);

    aggregate_kernel<64><<<ab, 256, 0, stream>>>(h2, offs, csr, invd, mean, N);
    gemm_relu_stream<64, 32, R><<<g3, 256, 0, stream>>>(mean, h2, w3l, w3r, b3l, h3, N);

    classifier_kernel<<<(N + 255) / 256, 256, 0, stream>>>(h3, wc, bc, out, N);
}